// Round 3
// baseline (5008.073 us; speedup 1.0000x reference)
//
#include <hip/hip_runtime.h>
#include <hip/hip_bf16.h>

#define V_SIZE   50257
#define D_DIM    1024
#define N_ROWS   4096
#define N_CHUNKS 128
#define K_CAND   2048
#define SCALE_F  20.0f
#define AUX_F    0.2f
#define NEG_BIG  -1e30f

// workspace offsets (float units)
#define OFF_INVF   0
#define OFF_INVL   50304
#define OFF_HINV   100608
#define OFF_HMEAN  104704
#define OFF_POSF   112896
#define OFF_POSL   116992
#define OFF_CLOSS  121088
#define OFF_PMF    121216
#define OFF_PSF    153984
#define OFF_PML    186752
#define OFF_PSL    219520
#define OFF_SCAN   252288
#define OFF_TOPI   6685184   /* ints from here; total ~26.5 MiB */

__device__ __forceinline__ unsigned f2u_ord(float x) {
    unsigned u = __float_as_uint(x);
    return (u & 0x80000000u) ? ~u : (u | 0x80000000u);
}

// ---------------- K1: per-vocab norms ----------------
__global__ __launch_bounds__(256) void k_vnorm(const float* __restrict__ E,
                                               float* __restrict__ inv_full,
                                               float* __restrict__ inv_low) {
    const int v = blockIdx.x;
    const int tid = threadIdx.x;
    const float* row = E + (size_t)v * D_DIM;
    float ss = 0.f, sl = 0.f;
    for (int k = tid; k < D_DIM; k += 256) {
        float x = row[k];
        ss += x * x;
        if (k < 64) sl += x * x;
    }
    __shared__ float red[2][256];
    red[0][tid] = ss; red[1][tid] = sl;
    __syncthreads();
    for (int s = 128; s > 0; s >>= 1) {
        if (tid < s) { red[0][tid] += red[0][tid + s]; red[1][tid] += red[1][tid + s]; }
        __syncthreads();
    }
    if (tid == 0) {
        inv_full[v] = 1.f / fmaxf(sqrtf(red[0][0]), 1e-12f);
        inv_low[v]  = 1.f / fmaxf(sqrtf(red[1][0]), 1e-12f);
    }
}

// ---------------- K2: h row inv-norms + chunk means ----------------
__global__ __launch_bounds__(256) void k_hstats(const float* __restrict__ H,
                                                float* __restrict__ h_inv,
                                                float* __restrict__ h_mean) {
    const int c = blockIdx.x;
    const int tid = threadIdx.x;
    __shared__ float red[256];
    __shared__ float hinv_s[32];
    for (int i = 0; i < 32; ++i) {
        const float* row = H + (size_t)(c * 32 + i) * D_DIM;
        float ss = 0.f;
        for (int k = tid; k < D_DIM; k += 256) { float x = row[k]; ss += x * x; }
        red[tid] = ss;
        __syncthreads();
        for (int s = 128; s > 0; s >>= 1) {
            if (tid < s) red[tid] += red[tid + s];
            __syncthreads();
        }
        if (tid == 0) {
            float inv = 1.f / fmaxf(sqrtf(red[0]), 1e-6f);
            hinv_s[i] = inv;
            h_inv[c * 32 + i] = inv;
        }
        __syncthreads();
    }
    if (tid < 64) {
        float sum = 0.f;
        for (int i = 0; i < 32; ++i)
            sum += H[(size_t)(c * 32 + i) * D_DIM + tid] * hinv_s[i];
        h_mean[c * 64 + tid] = sum * (1.f / 32.f);
    }
}

// ---------------- K3: scan logits S[c][v] ----------------
__global__ __launch_bounds__(256) void k_scan(const float* __restrict__ E,
                                              const float* __restrict__ h_mean,
                                              const float* __restrict__ inv_low,
                                              float* __restrict__ S) {
    __shared__ float hm[N_CHUNKS * 64];   // 32 KiB
    for (int idx = threadIdx.x; idx < N_CHUNKS * 64; idx += 256) hm[idx] = h_mean[idx];
    __syncthreads();
    const int v = blockIdx.x * 256 + threadIdx.x;
    if (v >= V_SIZE) return;
    float e[64];
    const float4* row = (const float4*)(E + (size_t)v * D_DIM);
#pragma unroll
    for (int q = 0; q < 16; ++q) {
        float4 f = row[q];
        e[4*q] = f.x; e[4*q+1] = f.y; e[4*q+2] = f.z; e[4*q+3] = f.w;
    }
    const float inv = inv_low[v];
    for (int c = 0; c < N_CHUNKS; ++c) {
        const float4* hmc = (const float4*)&hm[c * 64];
        float d = 0.f;
#pragma unroll
        for (int q = 0; q < 16; ++q) {
            float4 h4 = hmc[q];
            d += e[4*q] * h4.x + e[4*q+1] * h4.y + e[4*q+2] * h4.z + e[4*q+3] * h4.w;
        }
        S[(size_t)c * V_SIZE + v] = d * inv;
    }
}

// ---------------- K4: exact top-2048 per chunk (radix select) ----------------
__global__ __launch_bounds__(256) void k_topk(const float* __restrict__ S,
                                              int* __restrict__ topi) {
    const int c = blockIdx.x;
    const int tid = threadIdx.x;
    const float* s = S + (size_t)c * V_SIZE;
    __shared__ unsigned hist[2048];
    __shared__ unsigned st[8];
    __shared__ int cnts[2];

    // pass 1: bits 31..21
    for (int i = tid; i < 2048; i += 256) hist[i] = 0u;
    __syncthreads();
    for (int v = tid; v < V_SIZE; v += 256) {
        unsigned u = f2u_ord(s[v]);
        atomicAdd(&hist[u >> 21], 1u);
    }
    __syncthreads();
    if (tid == 0) {
        unsigned cum = 0u;
        for (unsigned b = 2047u;; --b) {
            unsigned c2 = cum + hist[b];
            if (c2 >= (unsigned)K_CAND || b == 0u) { st[0] = b; st[1] = (unsigned)K_CAND - cum; break; }
            cum = c2;
        }
    }
    __syncthreads();
    const unsigned b1 = st[0], krem1 = st[1];

    // pass 2: bits 20..10
    for (int i = tid; i < 2048; i += 256) hist[i] = 0u;
    __syncthreads();
    for (int v = tid; v < V_SIZE; v += 256) {
        unsigned u = f2u_ord(s[v]);
        if ((u >> 21) == b1) atomicAdd(&hist[(u >> 10) & 0x7FFu], 1u);
    }
    __syncthreads();
    if (tid == 0) {
        unsigned cum = 0u;
        for (unsigned b = 2047u;; --b) {
            unsigned c2 = cum + hist[b];
            if (c2 >= krem1 || b == 0u) { st[2] = b; st[3] = krem1 - cum; break; }
            cum = c2;
        }
    }
    __syncthreads();
    const unsigned b2 = st[2], krem2 = st[3];
    const unsigned pref22 = (b1 << 11) | b2;

    // pass 3: bits 9..0
    for (int i = tid; i < 2048; i += 256) hist[i] = 0u;
    __syncthreads();
    for (int v = tid; v < V_SIZE; v += 256) {
        unsigned u = f2u_ord(s[v]);
        if ((u >> 10) == pref22) atomicAdd(&hist[u & 0x3FFu], 1u);
    }
    __syncthreads();
    if (tid == 0) {
        unsigned cum = 0u;
        for (unsigned b = 1023u;; --b) {
            unsigned c2 = cum + hist[b];
            if (c2 >= krem2 || b == 0u) { st[4] = b; st[5] = krem2 - cum; break; }
            cum = c2;
        }
        cnts[0] = 0; cnts[1] = 0;
    }
    __syncthreads();
    const unsigned T = (pref22 << 10) | st[4];
    const unsigned neq = st[5];

    // compaction
    int* eql = (int*)hist;   // reuse
    int* out = topi + (size_t)c * K_CAND;
    for (int v = tid; v < V_SIZE; v += 256) {
        unsigned u = f2u_ord(s[v]);
        if (u > T) { int p = atomicAdd(&cnts[0], 1); out[p] = v; }
        else if (u == T) { int p = atomicAdd(&cnts[1], 1); if (p < 2048) eql[p] = v; }
    }
    __syncthreads();
    if (tid == 0) {
        int ne = cnts[1] < 2048 ? cnts[1] : 2048;
        int base = cnts[0];
        for (int r = 0; r < (int)neq; ++r) {
            int best = 0x7FFFFFFF, bq = -1;
            for (int q = 0; q < ne; ++q) {
                int x = eql[q];
                if (x >= 0 && x < best) { best = x; bq = q; }
            }
            if (bq >= 0) { eql[bq] = -1; out[base + r] = best; }
            else out[base + r] = 0;   // unreachable safety fill
        }
    }
}

// ---------------- K5: positive sims ----------------
__global__ __launch_bounds__(256) void k_pos(const float* __restrict__ H,
                                             const float* __restrict__ E,
                                             const int* __restrict__ tgt,
                                             const float* __restrict__ h_inv,
                                             const float* __restrict__ inv_full,
                                             const float* __restrict__ inv_low,
                                             float* __restrict__ pos_f,
                                             float* __restrict__ pos_l) {
    const int i = blockIdx.x;
    const int tid = threadIdx.x;
    const int t = tgt[i];
    const float* h = H + (size_t)i * D_DIM;
    const float* w = E + (size_t)t * D_DIM;
    float sf = 0.f, sl = 0.f;
    for (int k = tid; k < D_DIM; k += 256) {
        float p = h[k] * w[k];
        sf += p;
        if (k < 64) sl += p;
    }
    __shared__ float red[2][256];
    red[0][tid] = sf; red[1][tid] = sl;
    __syncthreads();
    for (int s = 128; s > 0; s >>= 1) {
        if (tid < s) { red[0][tid] += red[0][tid + s]; red[1][tid] += red[1][tid + s]; }
        __syncthreads();
    }
    if (tid == 0) {
        pos_f[i] = red[0][0] * h_inv[i] * inv_full[t];
        pos_l[i] = red[1][0] * h_inv[i] * inv_low[t];
    }
}

// ---------------- K6: negative sims + per-block online softmax partials ----------------
__device__ __forceinline__ void kloop32(const float (*e_t)[256], const float (*h_t)[32],
                                        int ti, int tj, float (&accf)[8][4], float (&accl)[8][4],
                                        bool dolow) {
#pragma unroll
    for (int k = 0; k < 32; ++k) {
        const float4 ej = *(const float4*)&e_t[k][tj * 4];
        const float4 ha = *(const float4*)&h_t[k][ti * 8];
        const float4 hb = *(const float4*)&h_t[k][ti * 8 + 4];
        const float er[4] = {ej.x, ej.y, ej.z, ej.w};
        const float hr[8] = {ha.x, ha.y, ha.z, ha.w, hb.x, hb.y, hb.z, hb.w};
#pragma unroll
        for (int a = 0; a < 8; ++a)
#pragma unroll
            for (int b = 0; b < 4; ++b)
                accf[a][b] = fmaf(hr[a], er[b], accf[a][b]);
        if (dolow) {
#pragma unroll
            for (int a = 0; a < 8; ++a)
#pragma unroll
                for (int b = 0; b < 4; ++b)
                    accl[a][b] = fmaf(hr[a], er[b], accl[a][b]);
        }
    }
}

__device__ __forceinline__ void row_reduce_store(const float (*lg)[256], int ti, int tj,
                                                 float* __restrict__ pm, float* __restrict__ ps) {
    for (int r = 0; r < 8; ++r) {
        const int i = ti * 8 + r;
        const float v0 = lg[i][tj], v1 = lg[i][tj + 64], v2 = lg[i][tj + 128], v3 = lg[i][tj + 192];
        float m = fmaxf(fmaxf(v0, v1), fmaxf(v2, v3));
#pragma unroll
        for (int off = 32; off; off >>= 1) m = fmaxf(m, __shfl_xor(m, off));
        float s = __expf(v0 - m) + __expf(v1 - m) + __expf(v2 - m) + __expf(v3 - m);
#pragma unroll
        for (int off = 32; off; off >>= 1) s += __shfl_xor(s, off);
        if (tj == 0) { pm[i] = m; ps[i] = s; }
    }
}

__global__ __launch_bounds__(256) void k_neg(const float* __restrict__ H,
                                             const float* __restrict__ E,
                                             const int* __restrict__ tgt,
                                             const int* __restrict__ topi,
                                             const float* __restrict__ h_inv,
                                             const float* __restrict__ inv_full,
                                             const float* __restrict__ inv_low,
                                             float* __restrict__ pm_f, float* __restrict__ ps_f,
                                             float* __restrict__ pm_l, float* __restrict__ ps_l) {
    const int c  = blockIdx.x >> 3;
    const int jb = blockIdx.x & 7;
    const int tid = threadIdx.x;
    const int ti = tid >> 6;   // row group (also wave id)
    const int tj = tid & 63;   // lane / candidate group

    __shared__ float e_t[32][256];   // [k][j], reused as logits[32 rows][256 j]
    __shared__ float h_t[32][32];    // [k][i]
    __shared__ float hinv_s[32];
    __shared__ int   tgt_s[32];
    __shared__ int   cand_s[256];
    __shared__ float invf_s[256];
    __shared__ float invl_s[256];

    if (tid < 32) { hinv_s[tid] = h_inv[c * 32 + tid]; tgt_s[tid] = tgt[c * 32 + tid]; }
    {
        const int cd = topi[(size_t)c * K_CAND + jb * 256 + tid];
        cand_s[tid] = cd;
        invf_s[tid] = inv_full[cd];
        invl_s[tid] = inv_low[cd];
    }
    __syncthreads();

    const int hi = tid >> 3;
    const int hk = (tid & 7) * 4;
    const float hinv_mine = hinv_s[hi];
    const float* hrow = H + (size_t)(c * 32 + hi) * D_DIM;
    const float* erow = E + (size_t)cand_s[tid] * D_DIM;

    float accf[8][4], accl[8][4];
#pragma unroll
    for (int a = 0; a < 8; ++a)
#pragma unroll
        for (int b = 0; b < 4; ++b) { accf[a][b] = 0.f; accl[a][b] = 0.f; }

    for (int kt = 0; kt < 32; ++kt) {
        __syncthreads();
        {
            const float4 hv = *(const float4*)(hrow + kt * 32 + hk);
            h_t[hk + 0][hi] = hv.x * hinv_mine;
            h_t[hk + 1][hi] = hv.y * hinv_mine;
            h_t[hk + 2][hi] = hv.z * hinv_mine;
            h_t[hk + 3][hi] = hv.w * hinv_mine;
            const float4* ev = (const float4*)(erow + kt * 32);
#pragma unroll
            for (int q = 0; q < 8; ++q) {
                const float4 e4 = ev[q];
                e_t[q * 4 + 0][tid] = e4.x;
                e_t[q * 4 + 1][tid] = e4.y;
                e_t[q * 4 + 2][tid] = e4.z;
                e_t[q * 4 + 3][tid] = e4.w;
            }
        }
        __syncthreads();
        kloop32(e_t, h_t, ti, tj, accf, accl, kt < 2);
    }

    // ---- full-rank logits ----
    __syncthreads();
#pragma unroll
    for (int a = 0; a < 8; ++a) {
        const int i = ti * 8 + a;
        const int t_i = tgt_s[i];
#pragma unroll
        for (int b = 0; b < 4; ++b) {
            const int j = tj * 4 + b;
            float lg = SCALE_F * accf[a][b] * invf_s[j];
            if (cand_s[j] == t_i) lg = NEG_BIG;
            e_t[i][j] = lg;
        }
    }
    __syncthreads();
    row_reduce_store(e_t, ti, tj, pm_f + ((size_t)c * 8 + jb) * 32, ps_f + ((size_t)c * 8 + jb) * 32);
    __syncthreads();
    // ---- low-rank logits ----
#pragma unroll
    for (int a = 0; a < 8; ++a) {
        const int i = ti * 8 + a;
        const int t_i = tgt_s[i];
#pragma unroll
        for (int b = 0; b < 4; ++b) {
            const int j = tj * 4 + b;
            float lg = SCALE_F * accl[a][b] * invl_s[j];
            if (cand_s[j] == t_i) lg = NEG_BIG;
            e_t[i][j] = lg;
        }
    }
    __syncthreads();
    row_reduce_store(e_t, ti, tj, pm_l + ((size_t)c * 8 + jb) * 32, ps_l + ((size_t)c * 8 + jb) * 32);
}

// ---------------- K7: combine partials -> per-chunk loss ----------------
__global__ void k_loss(const float* __restrict__ pm_f, const float* __restrict__ ps_f,
                       const float* __restrict__ pm_l, const float* __restrict__ ps_l,
                       const float* __restrict__ pos_f, const float* __restrict__ pos_l,
                       float* __restrict__ closs) {
    const int c = blockIdx.x;
    const int tid = threadIdx.x;   // 64
    float val = 0.f;
    if (tid < 32) {
        const int i = tid;
        float lm, la;
        {
            float M = NEG_BIG;
            for (int jb = 0; jb < 8; ++jb) M = fmaxf(M, pm_f[((size_t)c * 8 + jb) * 32 + i]);
            float S = 0.f;
            for (int jb = 0; jb < 8; ++jb)
                S += ps_f[((size_t)c * 8 + jb) * 32 + i] * __expf(pm_f[((size_t)c * 8 + jb) * 32 + i] - M);
            const float p = SCALE_F * pos_f[c * 32 + i];
            const float M2 = fmaxf(M, p);
            const float S2 = __expf(p - M2) + S * __expf(M - M2);
            lm = (M2 + __logf(S2)) - p;
        }
        {
            float M = NEG_BIG;
            for (int jb = 0; jb < 8; ++jb) M = fmaxf(M, pm_l[((size_t)c * 8 + jb) * 32 + i]);
            float S = 0.f;
            for (int jb = 0; jb < 8; ++jb)
                S += ps_l[((size_t)c * 8 + jb) * 32 + i] * __expf(pm_l[((size_t)c * 8 + jb) * 32 + i] - M);
            const float p = SCALE_F * pos_l[c * 32 + i];
            const float M2 = fmaxf(M, p);
            const float S2 = __expf(p - M2) + S * __expf(M - M2);
            la = (M2 + __logf(S2)) - p;
        }
        val = lm + AUX_F * la;
    }
#pragma unroll
    for (int off = 32; off; off >>= 1) val += __shfl_xor(val, off);
    if (tid == 0) closs[c] = val;
}

// ---------------- K8: final scalar ----------------
__global__ void k_final(const float* __restrict__ closs, float* __restrict__ out) {
    const int tid = threadIdx.x;   // 64
    float v = closs[tid] + closs[tid + 64];
#pragma unroll
    for (int off = 32; off; off >>= 1) v += __shfl_xor(v, off);
    if (tid == 0) out[0] = v * (1.f / (float)N_ROWS);
}

extern "C" void kernel_launch(void* const* d_in, const int* in_sizes, int n_in,
                              void* d_out, int out_size, void* d_ws, size_t ws_size,
                              hipStream_t stream) {
    const float* H   = (const float*)d_in[0];
    const float* E   = (const float*)d_in[1];
    const int*   tgt = (const int*)d_in[2];
    float* out = (float*)d_out;
    float* w = (float*)d_ws;

    float* inv_full = w + OFF_INVF;
    float* inv_low  = w + OFF_INVL;
    float* h_inv    = w + OFF_HINV;
    float* h_mean   = w + OFF_HMEAN;
    float* pos_f    = w + OFF_POSF;
    float* pos_l    = w + OFF_POSL;
    float* closs    = w + OFF_CLOSS;
    float* pm_f     = w + OFF_PMF;
    float* ps_f     = w + OFF_PSF;
    float* pm_l     = w + OFF_PML;
    float* ps_l     = w + OFF_PSL;
    float* scan     = w + OFF_SCAN;
    int*   topi     = (int*)(w + OFF_TOPI);

    k_vnorm <<<V_SIZE, 256, 0, stream>>>(E, inv_full, inv_low);
    k_hstats<<<N_CHUNKS, 256, 0, stream>>>(H, h_inv, h_mean);
    k_scan  <<<(V_SIZE + 255) / 256, 256, 0, stream>>>(E, h_mean, inv_low, scan);
    k_topk  <<<N_CHUNKS, 256, 0, stream>>>(scan, topi);
    k_pos   <<<N_ROWS, 256, 0, stream>>>(H, E, tgt, h_inv, inv_full, inv_low, pos_f, pos_l);
    k_neg   <<<N_CHUNKS * 8, 256, 0, stream>>>(H, E, tgt, topi, h_inv, inv_full, inv_low,
                                               pm_f, ps_f, pm_l, ps_l);
    k_loss  <<<N_CHUNKS, 64, 0, stream>>>(pm_f, ps_f, pm_l, ps_l, pos_f, pos_l, closs);
    k_final <<<1, 64, 0, stream>>>(closs, out);
}

// Round 5
// 1016.737 us; speedup vs baseline: 4.9256x; 4.9256x over previous
//
#include <hip/hip_runtime.h>
#include <hip/hip_bf16.h>

#define V_SIZE   50257
#define D_DIM    1024
#define N_ROWS   4096
#define N_CHUNKS 128
#define K_CAND   2048
#define SCALE_F  20.0f
#define AUX_F    0.2f
#define NEG_BIG  -1e30f

// workspace offsets (float units)
#define OFF_INVF   0
#define OFF_INVL   50304
#define OFF_HINV   100608
#define OFF_HMEAN  104704
#define OFF_POSF   112896
#define OFF_POSL   116992
#define OFF_CLOSS  121088
#define OFF_PMF    121216
#define OFF_PSF    153984
#define OFF_PML    186752
#define OFF_PSL    219520
#define OFF_SCAN   252288
#define OFF_TOPI   6685184   // ints from here (128*2048 ints = 1 MiB)
#define OFF_HNBF   6947328   // ushorts from here (4096*1024 bf16 = 8 MiB); ws total ~36 MiB

typedef short bf16x8 __attribute__((ext_vector_type(8)));
typedef float f32x4  __attribute__((ext_vector_type(4)));

__device__ __forceinline__ unsigned f2u_ord(float x) {
    unsigned u = __float_as_uint(x);
    return (u & 0x80000000u) ? ~u : (u | 0x80000000u);
}

// fp32 -> bf16 round-to-nearest-even, as raw ushort bits
__device__ __forceinline__ unsigned f2bf(float x) {
    unsigned u = __float_as_uint(x);
    return (u + 0x7FFFu + ((u >> 16) & 1u)) >> 16;
}

// ---------------- K1: per-vocab norms ----------------
__global__ __launch_bounds__(256) void k_vnorm(const float* __restrict__ E,
                                               float* __restrict__ inv_full,
                                               float* __restrict__ inv_low) {
    const int v = blockIdx.x;
    const int tid = threadIdx.x;
    const float* row = E + (size_t)v * D_DIM;
    float ss = 0.f, sl = 0.f;
    for (int k = tid; k < D_DIM; k += 256) {
        float x = row[k];
        ss += x * x;
        if (k < 64) sl += x * x;
    }
    __shared__ float red[2][256];
    red[0][tid] = ss; red[1][tid] = sl;
    __syncthreads();
    for (int s = 128; s > 0; s >>= 1) {
        if (tid < s) { red[0][tid] += red[0][tid + s]; red[1][tid] += red[1][tid + s]; }
        __syncthreads();
    }
    if (tid == 0) {
        inv_full[v] = 1.f / fmaxf(sqrtf(red[0][0]), 1e-12f);
        inv_low[v]  = 1.f / fmaxf(sqrtf(red[1][0]), 1e-12f);
    }
}

// ---------------- K2: h row inv-norms + chunk means + normalized-H bf16 cast ----------------
__global__ __launch_bounds__(256) void k_hstats(const float* __restrict__ H,
                                                float* __restrict__ h_inv,
                                                float* __restrict__ h_mean,
                                                unsigned short* __restrict__ Hnbf) {
    const int c = blockIdx.x;
    const int tid = threadIdx.x;
    __shared__ float red[256];
    __shared__ float hinv_s[32];
    for (int i = 0; i < 32; ++i) {
        const float* row = H + (size_t)(c * 32 + i) * D_DIM;
        float ss = 0.f;
        for (int k = tid; k < D_DIM; k += 256) { float x = row[k]; ss += x * x; }
        red[tid] = ss;
        __syncthreads();
        for (int s = 128; s > 0; s >>= 1) {
            if (tid < s) red[tid] += red[tid + s];
            __syncthreads();
        }
        if (tid == 0) {
            float inv = 1.f / fmaxf(sqrtf(red[0]), 1e-6f);
            hinv_s[i] = inv;
            h_inv[c * 32 + i] = inv;
        }
        __syncthreads();
    }
    // normalized bf16 cast: h_full = H * h_inv
    for (int i = 0; i < 32; ++i) {
        const int r = c * 32 + i;
        const float inv = hinv_s[i];
        const float4 v = *(const float4*)(H + (size_t)r * D_DIM + tid * 4);
        uint2 p;
        p.x = f2bf(v.x * inv) | (f2bf(v.y * inv) << 16);
        p.y = f2bf(v.z * inv) | (f2bf(v.w * inv) << 16);
        *(uint2*)&Hnbf[(size_t)r * D_DIM + tid * 4] = p;
    }
    if (tid < 64) {
        float sum = 0.f;
        for (int i = 0; i < 32; ++i)
            sum += H[(size_t)(c * 32 + i) * D_DIM + tid] * hinv_s[i];
        h_mean[c * 64 + tid] = sum * (1.f / 32.f);
    }
}

// ---------------- K3: scan logits S[c][v] (reads E[:, :64] only) ----------------
__global__ __launch_bounds__(256) void k_scan(const float* __restrict__ E,
                                              const float* __restrict__ h_mean,
                                              const float* __restrict__ inv_low,
                                              float* __restrict__ S) {
    __shared__ float hm[N_CHUNKS * 64];   // 32 KiB
    for (int idx = threadIdx.x; idx < N_CHUNKS * 64; idx += 256) hm[idx] = h_mean[idx];
    __syncthreads();
    const int v = blockIdx.x * 256 + threadIdx.x;
    if (v >= V_SIZE) return;
    float e[64];
    const float4* row = (const float4*)(E + (size_t)v * D_DIM);
#pragma unroll
    for (int q = 0; q < 16; ++q) {
        float4 f = row[q];
        e[4*q] = f.x; e[4*q+1] = f.y; e[4*q+2] = f.z; e[4*q+3] = f.w;
    }
    const float inv = inv_low[v];
    for (int c = 0; c < N_CHUNKS; ++c) {
        const float4* hmc = (const float4*)&hm[c * 64];
        float d = 0.f;
#pragma unroll
        for (int q = 0; q < 16; ++q) {
            float4 h4 = hmc[q];
            d += e[4*q] * h4.x + e[4*q+1] * h4.y + e[4*q+2] * h4.z + e[4*q+3] * h4.w;
        }
        S[(size_t)c * V_SIZE + v] = d * inv;
    }
}

// ---------------- K4: exact top-2048 per chunk (radix select) ----------------
__global__ __launch_bounds__(256) void k_topk(const float* __restrict__ S,
                                              int* __restrict__ topi) {
    const int c = blockIdx.x;
    const int tid = threadIdx.x;
    const float* s = S + (size_t)c * V_SIZE;
    __shared__ unsigned hist[2048];
    __shared__ unsigned st[8];
    __shared__ int cnts[2];

    for (int i = tid; i < 2048; i += 256) hist[i] = 0u;
    __syncthreads();
    for (int v = tid; v < V_SIZE; v += 256) {
        unsigned u = f2u_ord(s[v]);
        atomicAdd(&hist[u >> 21], 1u);
    }
    __syncthreads();
    if (tid == 0) {
        unsigned cum = 0u;
        for (unsigned b = 2047u;; --b) {
            unsigned c2 = cum + hist[b];
            if (c2 >= (unsigned)K_CAND || b == 0u) { st[0] = b; st[1] = (unsigned)K_CAND - cum; break; }
            cum = c2;
        }
    }
    __syncthreads();
    const unsigned b1 = st[0], krem1 = st[1];

    for (int i = tid; i < 2048; i += 256) hist[i] = 0u;
    __syncthreads();
    for (int v = tid; v < V_SIZE; v += 256) {
        unsigned u = f2u_ord(s[v]);
        if ((u >> 21) == b1) atomicAdd(&hist[(u >> 10) & 0x7FFu], 1u);
    }
    __syncthreads();
    if (tid == 0) {
        unsigned cum = 0u;
        for (unsigned b = 2047u;; --b) {
            unsigned c2 = cum + hist[b];
            if (c2 >= krem1 || b == 0u) { st[2] = b; st[3] = krem1 - cum; break; }
            cum = c2;
        }
    }
    __syncthreads();
    const unsigned b2 = st[2], krem2 = st[3];
    const unsigned pref22 = (b1 << 11) | b2;

    for (int i = tid; i < 2048; i += 256) hist[i] = 0u;
    __syncthreads();
    for (int v = tid; v < V_SIZE; v += 256) {
        unsigned u = f2u_ord(s[v]);
        if ((u >> 10) == pref22) atomicAdd(&hist[u & 0x3FFu], 1u);
    }
    __syncthreads();
    if (tid == 0) {
        unsigned cum = 0u;
        for (unsigned b = 1023u;; --b) {
            unsigned c2 = cum + hist[b];
            if (c2 >= krem2 || b == 0u) { st[4] = b; st[5] = krem2 - cum; break; }
            cum = c2;
        }
        cnts[0] = 0; cnts[1] = 0;
    }
    __syncthreads();
    const unsigned T = (pref22 << 10) | st[4];
    const unsigned neq = st[5];

    int* eql = (int*)hist;
    int* out = topi + (size_t)c * K_CAND;
    for (int v = tid; v < V_SIZE; v += 256) {
        unsigned u = f2u_ord(s[v]);
        if (u > T) { int p = atomicAdd(&cnts[0], 1); out[p] = v; }
        else if (u == T) { int p = atomicAdd(&cnts[1], 1); if (p < 2048) eql[p] = v; }
    }
    __syncthreads();
    if (tid == 0) {
        int ne = cnts[1] < 2048 ? cnts[1] : 2048;
        int base = cnts[0];
        for (int r = 0; r < (int)neq; ++r) {
            int best = 0x7FFFFFFF, bq = -1;
            for (int q = 0; q < ne; ++q) {
                int x = eql[q];
                if (x >= 0 && x < best) { best = x; bq = q; }
            }
            if (bq >= 0) { eql[bq] = -1; out[base + r] = best; }
            else out[base + r] = 0;
        }
    }
}

// ---------------- K5: positive sims (exact fp32) ----------------
__global__ __launch_bounds__(256) void k_pos(const float* __restrict__ H,
                                             const float* __restrict__ E,
                                             const int* __restrict__ tgt,
                                             const float* __restrict__ h_inv,
                                             const float* __restrict__ inv_full,
                                             const float* __restrict__ inv_low,
                                             float* __restrict__ pos_f,
                                             float* __restrict__ pos_l) {
    const int i = blockIdx.x;
    const int tid = threadIdx.x;
    const int t = tgt[i];
    const float* h = H + (size_t)i * D_DIM;
    const float* w = E + (size_t)t * D_DIM;
    float sf = 0.f, sl = 0.f;
    for (int k = tid; k < D_DIM; k += 256) {
        float p = h[k] * w[k];
        sf += p;
        if (k < 64) sl += p;
    }
    __shared__ float red[2][256];
    red[0][tid] = sf; red[1][tid] = sl;
    __syncthreads();
    for (int s = 128; s > 0; s >>= 1) {
        if (tid < s) { red[0][tid] += red[0][tid + s]; red[1][tid] += red[1][tid + s]; }
        __syncthreads();
    }
    if (tid == 0) {
        pos_f[i] = red[0][0] * h_inv[i] * inv_full[t];
        pos_l[i] = red[1][0] * h_inv[i] * inv_low[t];
    }
}

// ---------------- K6: MFMA negative sims + per-block online softmax partials ----------------
// 256-cand logits, stride-260 padded (conflict-free row reduce)
__device__ __forceinline__ void row_reduce_store(const float* __restrict__ lg, int ti, int tj,
                                                 float* __restrict__ pm, float* __restrict__ ps) {
#pragma unroll
    for (int r = 0; r < 8; ++r) {
        const int i = ti * 8 + r;
        const float v0 = lg[i*260 + tj],       v1 = lg[i*260 + tj + 64];
        const float v2 = lg[i*260 + tj + 128], v3 = lg[i*260 + tj + 192];
        float m = fmaxf(fmaxf(v0, v1), fmaxf(v2, v3));
#pragma unroll
        for (int off = 32; off; off >>= 1) m = fmaxf(m, __shfl_xor(m, off));
        float s = __expf(v0 - m) + __expf(v1 - m) + __expf(v2 - m) + __expf(v3 - m);
#pragma unroll
        for (int off = 32; off; off >>= 1) s += __shfl_xor(s, off);
        if (tj == 0) { pm[i] = m; ps[i] = s; }
    }
}

__global__ __launch_bounds__(256, 3) void k_neg(const float* __restrict__ E,
                                                const unsigned short* __restrict__ Hn,
                                                const int* __restrict__ tgt,
                                                const int* __restrict__ topi,
                                                const float* __restrict__ inv_full,
                                                const float* __restrict__ inv_low,
                                                float* __restrict__ pm_f, float* __restrict__ ps_f,
                                                float* __restrict__ pm_l, float* __restrict__ ps_l) {
    const int c  = blockIdx.x >> 3;
    const int jb = blockIdx.x & 7;
    const int tid  = threadIdx.x;
    const int w    = tid >> 6;    // wave id: cand-cols [w*64, w*64+64)
    const int lane = tid & 63;

    // union: staging tiles (e: 256x40 bf16 @0 = 20480B; h: 32x40 bf16 @20480 = 2560B)
    //        vs epilogue logits (32 x 260 f32 = 33280B)
    __shared__ __align__(16) char smem[33280];
    unsigned short* e_lds = (unsigned short*)smem;            // [cand][40] stride 80B: 8-phase conflict-free b128
    unsigned short* h_lds = (unsigned short*)(smem + 20480);  // [row][40]
    float*          lgts  = (float*)smem;                     // [32][260]
    __shared__ int   cand_s[256];
    __shared__ float invf_s[256];
    __shared__ float invl_s[256];
    __shared__ int   tgt_s[32];

    if (tid < 32) tgt_s[tid] = tgt[c * 32 + tid];
    const int cd = topi[(size_t)c * K_CAND + jb * 256 + tid];
    cand_s[tid] = cd;
    invf_s[tid] = inv_full[cd];
    invl_s[tid] = inv_low[cd];

    const float* erow = E + (size_t)cd * D_DIM;                      // this thread's cand row (fp32)
    const unsigned short* hsrc = Hn + (size_t)(c * 32 + (tid >> 2)) * D_DIM; // threads<128: h row tid>>2

    f32x4 accF[2][4], accL[2][4];
#pragma unroll
    for (int r = 0; r < 2; ++r)
#pragma unroll
        for (int n = 0; n < 4; ++n) {
            accF[r][n] = f32x4{0.f, 0.f, 0.f, 0.f};
            accL[r][n] = f32x4{0.f, 0.f, 0.f, 0.f};
        }

    const int frow = lane & 15;   // fragment row/col-within-16
    const int kg   = lane >> 4;   // k-group (8 bf16 each)

#pragma unroll 1
    for (int kt = 0; kt < 32; ++kt) {
        __syncthreads();   // previous tile's fragment reads done (also covers table init at kt=0)
        // stage E slice: this thread's cand, 32 fp32 -> 32 bf16
        {
            const float4* ep = (const float4*)(erow + kt * 32);
            unsigned short* ew = &e_lds[tid * 40];
#pragma unroll
            for (int q = 0; q < 4; ++q) {
                const float4 fa = ep[2*q], fb = ep[2*q+1];
                uint4 u;
                u.x = f2bf(fa.x) | (f2bf(fa.y) << 16);
                u.y = f2bf(fa.z) | (f2bf(fa.w) << 16);
                u.z = f2bf(fb.x) | (f2bf(fb.y) << 16);
                u.w = f2bf(fb.z) | (f2bf(fb.w) << 16);
                *(uint4*)&ew[q * 8] = u;
            }
        }
        // stage H slice: 32 rows x 32 bf16 (pre-normalized bf16) by threads 0..127
        if (tid < 128) {
            const int hq = tid & 3;
            const uint4 hv = *(const uint4*)(hsrc + kt * 32 + hq * 8);
            *(uint4*)&h_lds[(tid >> 2) * 40 + hq * 8] = hv;
        }
        __syncthreads();
        // fragments: A lane l holds A[row=l&15][k=8*(l>>4)+e]; B lane l holds B[k][col=l&15]
        const bf16x8 a0 = *(const bf16x8*)&h_lds[frow * 40 + kg * 8];
        const bf16x8 a1 = *(const bf16x8*)&h_lds[(frow + 16) * 40 + kg * 8];
#pragma unroll
        for (int n = 0; n < 4; ++n) {
            const bf16x8 b = *(const bf16x8*)&e_lds[(w * 64 + n * 16 + frow) * 40 + kg * 8];
            accF[0][n] = __builtin_amdgcn_mfma_f32_16x16x32_bf16(a0, b, accF[0][n], 0, 0, 0);
            accF[1][n] = __builtin_amdgcn_mfma_f32_16x16x32_bf16(a1, b, accF[1][n], 0, 0, 0);
            if (kt < 2) {   // low-rank = first 64 dims
                accL[0][n] = __builtin_amdgcn_mfma_f32_16x16x32_bf16(a0, b, accL[0][n], 0, 0, 0);
                accL[1][n] = __builtin_amdgcn_mfma_f32_16x16x32_bf16(a1, b, accL[1][n], 0, 0, 0);
            }
        }
    }

    // ---- full-rank logits: C/D map col=lane&15, row=(lane>>4)*4+reg ----
    __syncthreads();
#pragma unroll
    for (int r = 0; r < 2; ++r)
#pragma unroll
        for (int n = 0; n < 4; ++n)
#pragma unroll
            for (int q = 0; q < 4; ++q) {
                const int i = r * 16 + kg * 4 + q;
                const int j = w * 64 + n * 16 + frow;
                float lg = SCALE_F * accF[r][n][q] * invf_s[j];
                if (cand_s[j] == tgt_s[i]) lg = NEG_BIG;
                lgts[i * 260 + j] = lg;
            }
    __syncthreads();
    row_reduce_store(lgts, w, lane, pm_f + ((size_t)c * 8 + jb) * 32, ps_f + ((size_t)c * 8 + jb) * 32);
    __syncthreads();
    // ---- low-rank logits ----
#pragma unroll
    for (int r = 0; r < 2; ++r)
#pragma unroll
        for (int n = 0; n < 4; ++n)
#pragma unroll
            for (int q = 0; q < 4; ++q) {
                const int i = r * 16 + kg * 4 + q;
                const int j = w * 64 + n * 16 + frow;
                float lg = SCALE_F * accL[r][n][q] * invl_s[j];
                if (cand_s[j] == tgt_s[i]) lg = NEG_BIG;
                lgts[i * 260 + j] = lg;
            }
    __syncthreads();
    row_reduce_store(lgts, w, lane, pm_l + ((size_t)c * 8 + jb) * 32, ps_l + ((size_t)c * 8 + jb) * 32);
}

// ---------------- K7: combine partials -> per-chunk loss ----------------
__global__ void k_loss(const float* __restrict__ pm_f, const float* __restrict__ ps_f,
                       const float* __restrict__ pm_l, const float* __restrict__ ps_l,
                       const float* __restrict__ pos_f, const float* __restrict__ pos_l,
                       float* __restrict__ closs) {
    const int c = blockIdx.x;
    const int tid = threadIdx.x;   // 64
    float val = 0.f;
    if (tid < 32) {
        const int i = tid;
        float lm, la;
        {
            float M = NEG_BIG;
            for (int jb = 0; jb < 8; ++jb) M = fmaxf(M, pm_f[((size_t)c * 8 + jb) * 32 + i]);
            float S = 0.f;
            for (int jb = 0; jb < 8; ++jb)
                S += ps_f[((size_t)c * 8 + jb) * 32 + i] * __expf(pm_f[((size_t)c * 8 + jb) * 32 + i] - M);
            const float p = SCALE_F * pos_f[c * 32 + i];
            const float M2 = fmaxf(M, p);
            const float S2 = __expf(p - M2) + S * __expf(M - M2);
            lm = (M2 + __logf(S2)) - p;
        }
        {
            float M = NEG_BIG;
            for (int jb = 0; jb < 8; ++jb) M = fmaxf(M, pm_l[((size_t)c * 8 + jb) * 32 + i]);
            float S = 0.f;
            for (int jb = 0; jb < 8; ++jb)
                S += ps_l[((size_t)c * 8 + jb) * 32 + i] * __expf(pm_l[((size_t)c * 8 + jb) * 32 + i] - M);
            const float p = SCALE_F * pos_l[c * 32 + i];
            const float M2 = fmaxf(M, p);
            const float S2 = __expf(p - M2) + S * __expf(M - M2);
            la = (M2 + __logf(S2)) - p;
        }
        val = lm + AUX_F * la;
    }
#pragma unroll
    for (int off = 32; off; off >>= 1) val += __shfl_xor(val, off);
    if (tid == 0) closs[c] = val;
}

// ---------------- K8: final scalar ----------------
__global__ void k_final(const float* __restrict__ closs, float* __restrict__ out) {
    const int tid = threadIdx.x;   // 64
    float v = closs[tid] + closs[tid + 64];
#pragma unroll
    for (int off = 32; off; off >>= 1) v += __shfl_xor(v, off);
    if (tid == 0) out[0] = v * (1.f / (float)N_ROWS);
}

extern "C" void kernel_launch(void* const* d_in, const int* in_sizes, int n_in,
                              void* d_out, int out_size, void* d_ws, size_t ws_size,
                              hipStream_t stream) {
    const float* H   = (const float*)d_in[0];
    const float* E   = (const float*)d_in[1];
    const int*   tgt = (const int*)d_in[2];
    float* out = (float*)d_out;
    float* w = (float*)d_ws;

    float* inv_full = w + OFF_INVF;
    float* inv_low  = w + OFF_INVL;
    float* h_inv    = w + OFF_HINV;
    float* h_mean   = w + OFF_HMEAN;
    float* pos_f    = w + OFF_POSF;
    float* pos_l    = w + OFF_POSL;
    float* closs    = w + OFF_CLOSS;
    float* pm_f     = w + OFF_PMF;
    float* ps_f     = w + OFF_PSF;
    float* pm_l     = w + OFF_PML;
    float* ps_l     = w + OFF_PSL;
    float* scan     = w + OFF_SCAN;
    int*   topi     = (int*)(w + OFF_TOPI);
    unsigned short* Hnbf = (unsigned short*)(w + OFF_HNBF);

    k_vnorm <<<V_SIZE, 256, 0, stream>>>(E, inv_full, inv_low);
    k_hstats<<<N_CHUNKS, 256, 0, stream>>>(H, h_inv, h_mean, Hnbf);
    k_scan  <<<(V_SIZE + 255) / 256, 256, 0, stream>>>(E, h_mean, inv_low, scan);
    k_topk  <<<N_CHUNKS, 256, 0, stream>>>(scan, topi);
    k_pos   <<<N_ROWS, 256, 0, stream>>>(H, E, tgt, h_inv, inv_full, inv_low, pos_f, pos_l);
    k_neg   <<<N_CHUNKS * 8, 256, 0, stream>>>(E, Hnbf, tgt, topi, inv_full, inv_low,
                                               pm_f, ps_f, pm_l, ps_l);
    k_loss  <<<N_CHUNKS, 64, 0, stream>>>(pm_f, ps_f, pm_l, ps_l, pos_f, pos_l, closs);
    k_final <<<1, 64, 0, stream>>>(closs, out);
}

// Round 9
// 687.336 us; speedup vs baseline: 7.2862x; 1.4792x over previous
//
#include <hip/hip_runtime.h>
#include <hip/hip_bf16.h>

#define V_SIZE   50257
#define D_DIM    1024
#define N_ROWS   4096
#define N_CHUNKS 128
#define K_CAND   2048
#define SCALE_F  20.0f
#define AUX_F    0.2f
#define NEG_BIG  -1e30f
#define SEG_LEN  6283      /* ceil(V_SIZE/8) */
#define TKZERO   655360    /* gh1(256K)+gh2(256K)+gh3(128K) u32s */

// workspace offsets (4-byte units)
#define OFF_INVF   0
#define OFF_INVL   50304
#define OFF_HINV   100608
#define OFF_HMEAN  104704
#define OFF_POSF   112896
#define OFF_POSL   116992
#define OFF_CLOSS  121088
#define OFF_PMF    121216
#define OFF_PSF    153984
#define OFF_PML    186752
#define OFF_PSL    219520
#define OFF_SCAN   252288
#define OFF_TOPI   6685184   // 128*2048 ints
#define OFF_HNBF   6947328   // 4096*1024 bf16 = 2M slots
#define OFF_GH1    9044480   // 128*2048 u32
#define OFF_GH2    9306624   // 128*2048 u32
#define OFF_GH3    9568768   // 128*1024 u32
#define OFF_EQL    9699840   // 128*2048 ints
#define OFF_CNT    9961984   // 256 ints; ws end ~39.9 MB

typedef short bf16x8 __attribute__((ext_vector_type(8)));
typedef float f32x4  __attribute__((ext_vector_type(4)));

__device__ __forceinline__ unsigned f2u_ord(float x) {
    unsigned u = __float_as_uint(x);
    return (u & 0x80000000u) ? ~u : (u | 0x80000000u);
}

// fp32 -> bf16 round-to-nearest-even, as raw ushort bits
__device__ __forceinline__ unsigned f2bf(float x) {
    unsigned u = __float_as_uint(x);
    return (u + 0x7FFFu + ((u >> 16) & 1u)) >> 16;
}
__device__ __forceinline__ unsigned pk_bf16(float lo, float hi) {
    return f2bf(lo) | (f2bf(hi) << 16);
}

// ---------------- K1: per-vocab norms (wave-per-row, no LDS) ----------------
__global__ __launch_bounds__(256) void k_vnorm(const float* __restrict__ E,
                                               float* __restrict__ inv_full,
                                               float* __restrict__ inv_low) {
    const int wid = threadIdx.x >> 6, lane = threadIdx.x & 63;
    const int v = blockIdx.x * 4 + wid;
    if (v >= V_SIZE) return;
    const float* row = E + (size_t)v * D_DIM;
    float ss = 0.f, sl = 0.f;
#pragma unroll
    for (int it = 0; it < 4; ++it) {
        const float4 f = *(const float4*)(row + it * 256 + lane * 4);
        const float s4 = f.x*f.x + f.y*f.y + f.z*f.z + f.w*f.w;
        ss += s4;
        if (it == 0 && lane < 16) sl += s4;   // k = lane*4..lane*4+3 < 64
    }
#pragma unroll
    for (int off = 32; off; off >>= 1) { ss += __shfl_xor(ss, off); sl += __shfl_xor(sl, off); }
    if (lane == 0) {
        inv_full[v] = 1.f / fmaxf(sqrtf(ss), 1e-12f);
        inv_low[v]  = 1.f / fmaxf(sqrtf(sl), 1e-12f);
    }
}

// ---------------- K2: h inv-norms + chunk means + normalized-H bf16 ----------------
__global__ __launch_bounds__(256) void k_hstats(const float* __restrict__ H,
                                                float* __restrict__ h_inv,
                                                float* __restrict__ h_mean,
                                                unsigned short* __restrict__ Hnbf) {
    const int c = blockIdx.x, tid = threadIdx.x;
    const int wid = tid >> 6, lane = tid & 63;
    __shared__ float hinv_s[32];
    for (int i = wid; i < 32; i += 4) {       // wave-per-row, 8 rows/wave
        const float* row = H + (size_t)(c * 32 + i) * D_DIM;
        float ss = 0.f;
#pragma unroll
        for (int it = 0; it < 4; ++it) {
            const float4 f = *(const float4*)(row + it * 256 + lane * 4);
            ss += f.x*f.x + f.y*f.y + f.z*f.z + f.w*f.w;
        }
#pragma unroll
        for (int off = 32; off; off >>= 1) ss += __shfl_xor(ss, off);
        if (lane == 0) {
            const float inv = 1.f / fmaxf(sqrtf(ss), 1e-6f);
            hinv_s[i] = inv;
            h_inv[c * 32 + i] = inv;
        }
    }
    __syncthreads();
    // normalized bf16 cast
    for (int i = 0; i < 32; ++i) {
        const int r = c * 32 + i;
        const float inv = hinv_s[i];
        const float4 v = *(const float4*)(H + (size_t)r * D_DIM + tid * 4);
        uint2 p;
        p.x = pk_bf16(v.x * inv, v.y * inv);
        p.y = pk_bf16(v.z * inv, v.w * inv);
        *(uint2*)&Hnbf[(size_t)r * D_DIM + tid * 4] = p;
    }
    if (tid < 64) {
        float sum = 0.f;
        for (int i = 0; i < 32; ++i)
            sum += H[(size_t)(c * 32 + i) * D_DIM + tid] * hinv_s[i];
        h_mean[c * 64 + tid] = sum * (1.f / 32.f);
    }
}

// ---------------- K3: scan logits S[c][v] + zero topk scratch ----------------
__global__ __launch_bounds__(256) void k_scan(const float* __restrict__ E,
                                              const float* __restrict__ h_mean,
                                              const float* __restrict__ inv_low,
                                              float* __restrict__ S,
                                              unsigned* __restrict__ gz,
                                              int* __restrict__ cnt) {
    const int gtid = blockIdx.x * 256 + threadIdx.x;
    const int gstride = gridDim.x * 256;
    for (int i = gtid; i < TKZERO; i += gstride) gz[i] = 0u;
    if (gtid < 256) cnt[gtid] = 0;

    __shared__ float hm[N_CHUNKS * 64];   // 32 KiB
    for (int idx = threadIdx.x; idx < N_CHUNKS * 64; idx += 256) hm[idx] = h_mean[idx];
    __syncthreads();
    const int v = blockIdx.x * 256 + threadIdx.x;
    if (v >= V_SIZE) return;
    float e[64];
    const float4* row = (const float4*)(E + (size_t)v * D_DIM);
#pragma unroll
    for (int q = 0; q < 16; ++q) {
        float4 f = row[q];
        e[4*q] = f.x; e[4*q+1] = f.y; e[4*q+2] = f.z; e[4*q+3] = f.w;
    }
    const float inv = inv_low[v];
    for (int c = 0; c < N_CHUNKS; ++c) {
        const float4* hmc = (const float4*)&hm[c * 64];
        float d = 0.f;
#pragma unroll
        for (int q = 0; q < 16; ++q) {
            float4 h4 = hmc[q];
            d += e[4*q] * h4.x + e[4*q+1] * h4.y + e[4*q+2] * h4.z + e[4*q+3] * h4.w;
        }
        S[(size_t)c * V_SIZE + v] = d * inv;
    }
}

// ---------------- top-k helpers ----------------
// Block-parallel suffix-select over PER*256 bins: find b = max{bin : S(bin) >= Kt},
// krem = Kt - S(b+1), where S(bin) = sum_{i >= bin} gh[i]. Exactly-one-writer.
template<int PER>
__device__ __forceinline__ void suffix_sel(const unsigned* __restrict__ gh, unsigned Kt,
                                           int* out_b, unsigned* out_krem, unsigned* scr) {
    const int tid = threadIdx.x;
    __syncthreads();   // protect scr/out reuse across calls
    unsigned loc[PER];
    unsigned sum = 0;
#pragma unroll
    for (int j = 0; j < PER; ++j) { loc[j] = gh[tid * PER + j]; sum += loc[j]; }
    unsigned* a = scr; unsigned* b = scr + 256;
    a[tid] = sum;
    __syncthreads();
    for (int off = 1; off < 256; off <<= 1) {
        const unsigned v = a[tid] + ((tid + off) < 256 ? a[tid + off] : 0u);
        b[tid] = v;                // disjoint arrays: write-while-read safe
        __syncthreads();
        unsigned* t = a; a = b; b = t;
    }
    unsigned Ssuf = (tid + 1 < 256) ? a[tid + 1] : 0u;   // S(bin just past my range)
#pragma unroll
    for (int j = PER - 1; j >= 0; --j) {
        const unsigned Snext = Ssuf;
        Ssuf += loc[j];
        if (Ssuf >= Kt && Snext < Kt) { *out_b = tid * PER + j; *out_krem = Kt - Snext; }
    }
    __syncthreads();
}

// T1: level-1 histogram (bits 31..21), 8 segment-blocks per chunk
__global__ __launch_bounds__(256) void k_tkhist(const float* __restrict__ S,
                                                unsigned* __restrict__ gh1) {
    const int c = blockIdx.x >> 3, seg = blockIdx.x & 7, tid = threadIdx.x;
    __shared__ unsigned hist[2048];
    for (int i = tid; i < 2048; i += 256) hist[i] = 0u;
    __syncthreads();
    const float* s = S + (size_t)c * V_SIZE;
    const int v1 = min((seg + 1) * SEG_LEN, V_SIZE);
    for (int v = seg * SEG_LEN + tid; v < v1; v += 256)
        atomicAdd(&hist[f2u_ord(s[v]) >> 21], 1u);
    __syncthreads();
    for (int i = tid; i < 2048; i += 256) {
        const unsigned h = hist[i];
        if (h) atomicAdd(&gh1[c * 2048 + i], h);
    }
}

// T2: level-2 histogram (bits 20..10) among bucket b1
__global__ __launch_bounds__(256) void k_tksel2(const float* __restrict__ S,
                                                const unsigned* __restrict__ gh1,
                                                unsigned* __restrict__ gh2) {
    const int c = blockIdx.x >> 3, seg = blockIdx.x & 7, tid = threadIdx.x;
    __shared__ unsigned scr[512];
    __shared__ unsigned hist[2048];
    __shared__ int sb; __shared__ unsigned skrem;
    suffix_sel<8>(gh1 + c * 2048, K_CAND, &sb, &skrem, scr);
    const unsigned b1 = (unsigned)sb;
    for (int i = tid; i < 2048; i += 256) hist[i] = 0u;
    __syncthreads();
    const float* s = S + (size_t)c * V_SIZE;
    const int v1 = min((seg + 1) * SEG_LEN, V_SIZE);
    for (int v = seg * SEG_LEN + tid; v < v1; v += 256) {
        const unsigned u = f2u_ord(s[v]);
        if ((u >> 21) == b1) atomicAdd(&hist[(u >> 10) & 0x7FFu], 1u);
    }
    __syncthreads();
    for (int i = tid; i < 2048; i += 256) {
        const unsigned h = hist[i];
        if (h) atomicAdd(&gh2[c * 2048 + i], h);
    }
}

// T3: level-3 histogram (bits 9..0) among prefix (b1,b2)
__global__ __launch_bounds__(256) void k_tksel3(const float* __restrict__ S,
                                                const unsigned* __restrict__ gh1,
                                                const unsigned* __restrict__ gh2,
                                                unsigned* __restrict__ gh3) {
    const int c = blockIdx.x >> 3, seg = blockIdx.x & 7, tid = threadIdx.x;
    __shared__ unsigned scr[512];
    __shared__ unsigned hist[1024];
    __shared__ int sb; __shared__ unsigned skrem;
    suffix_sel<8>(gh1 + c * 2048, K_CAND, &sb, &skrem, scr);
    const unsigned b1 = (unsigned)sb;
    const unsigned krem1 = skrem;
    suffix_sel<8>(gh2 + c * 2048, krem1, &sb, &skrem, scr);
    const unsigned pref22 = (b1 << 11) | (unsigned)sb;
    for (int i = tid; i < 1024; i += 256) hist[i] = 0u;
    __syncthreads();
    const float* s = S + (size_t)c * V_SIZE;
    const int v1 = min((seg + 1) * SEG_LEN, V_SIZE);
    for (int v = seg * SEG_LEN + tid; v < v1; v += 256) {
        const unsigned u = f2u_ord(s[v]);
        if ((u >> 10) == pref22) atomicAdd(&hist[u & 0x3FFu], 1u);
    }
    __syncthreads();
    for (int i = tid; i < 1024; i += 256) {
        const unsigned h = hist[i];
        if (h) atomicAdd(&gh3[c * 1024 + i], h);
    }
}

// T4: threshold + compaction
__global__ __launch_bounds__(256) void k_tkcmp(const float* __restrict__ S,
                                               const unsigned* __restrict__ gh1,
                                               const unsigned* __restrict__ gh2,
                                               const unsigned* __restrict__ gh3,
                                               int* __restrict__ topi,
                                               int* __restrict__ eql,
                                               int* __restrict__ cnt) {
    const int c = blockIdx.x >> 3, seg = blockIdx.x & 7, tid = threadIdx.x;
    __shared__ unsigned scr[512];
    __shared__ int sb; __shared__ unsigned skrem;
    suffix_sel<8>(gh1 + c * 2048, K_CAND, &sb, &skrem, scr);
    const unsigned b1 = (unsigned)sb; const unsigned krem1 = skrem;
    suffix_sel<8>(gh2 + c * 2048, krem1, &sb, &skrem, scr);
    const unsigned b2 = (unsigned)sb; const unsigned krem2 = skrem;
    suffix_sel<4>(gh3 + c * 1024, krem2, &sb, &skrem, scr);
    const unsigned T = (b1 << 21) | (b2 << 10) | (unsigned)sb;
    const float* s = S + (size_t)c * V_SIZE;
    int* out = topi + (size_t)c * K_CAND;
    int* eq  = eql  + (size_t)c * K_CAND;
    const int v1 = min((seg + 1) * SEG_LEN, V_SIZE);
    for (int v = seg * SEG_LEN + tid; v < v1; v += 256) {
        const unsigned u = f2u_ord(s[v]);
        if (u > T)       { const int p = atomicAdd(&cnt[c * 2],     1); out[p] = v; }
        else if (u == T) { const int p = atomicAdd(&cnt[c * 2 + 1], 1); if (p < K_CAND) eq[p] = v; }
    }
}

// T5: tie-break (lowest index first, lax.top_k semantics)
__global__ __launch_bounds__(64) void k_tktie(const int* __restrict__ eql,
                                              const int* __restrict__ cnt,
                                              int* __restrict__ topi) {
    const int c = blockIdx.x, tid = threadIdx.x;
    __shared__ int buf[2048];
    const int base = cnt[c * 2];
    int ne = cnt[c * 2 + 1]; if (ne > K_CAND) ne = K_CAND;
    const int neq = K_CAND - base;
    for (int i = tid; i < ne; i += 64) buf[i] = eql[(size_t)c * K_CAND + i];
    __syncthreads();
    if (tid == 0) {
        int* out = topi + (size_t)c * K_CAND;
        for (int r = 0; r < neq; ++r) {
            int best = 0x7FFFFFFF, bq = -1;
            for (int q = 0; q < ne; ++q) if (buf[q] < best) { best = buf[q]; bq = q; }
            if (bq >= 0) { buf[bq] = 0x7FFFFFFF; out[base + r] = best; }
            else out[base + r] = 0;   // unreachable safety fill
        }
    }
}

// ---------------- K5: positive sims (exact fp32) ----------------
__global__ __launch_bounds__(256) void k_pos(const float* __restrict__ H,
                                             const float* __restrict__ E,
                                             const int* __restrict__ tgt,
                                             const float* __restrict__ h_inv,
                                             const float* __restrict__ inv_full,
                                             const float* __restrict__ inv_low,
                                             float* __restrict__ pos_f,
                                             float* __restrict__ pos_l) {
    const int i = blockIdx.x;
    const int tid = threadIdx.x;
    const int t = tgt[i];
    const float* h = H + (size_t)i * D_DIM;
    const float* w = E + (size_t)t * D_DIM;
    float sf = 0.f, sl = 0.f;
    for (int k = tid; k < D_DIM; k += 256) {
        const float p = h[k] * w[k];
        sf += p;
        if (k < 64) sl += p;
    }
    __shared__ float red[2][256];
    red[0][tid] = sf; red[1][tid] = sl;
    __syncthreads();
    for (int s = 128; s > 0; s >>= 1) {
        if (tid < s) { red[0][tid] += red[0][tid + s]; red[1][tid] += red[1][tid + s]; }
        __syncthreads();
    }
    if (tid == 0) {
        pos_f[i] = red[0][0] * h_inv[i] * inv_full[t];
        pos_l[i] = red[1][0] * h_inv[i] * inv_low[t];
    }
}

// ---------------- K6: MFMA negative sims + per-block online softmax partials ----------------
__device__ __forceinline__ void row_reduce_store(const float* __restrict__ lg, int ti, int tj,
                                                 float* __restrict__ pm, float* __restrict__ ps) {
#pragma unroll
    for (int r = 0; r < 8; ++r) {
        const int i = ti * 8 + r;
        const float v0 = lg[i*260 + tj],       v1 = lg[i*260 + tj + 64];
        const float v2 = lg[i*260 + tj + 128], v3 = lg[i*260 + tj + 192];
        float m = fmaxf(fmaxf(v0, v1), fmaxf(v2, v3));
#pragma unroll
        for (int off = 32; off; off >>= 1) m = fmaxf(m, __shfl_xor(m, off));
        float s = __expf(v0 - m) + __expf(v1 - m) + __expf(v2 - m) + __expf(v3 - m);
#pragma unroll
        for (int off = 32; off; off >>= 1) s += __shfl_xor(s, off);
        if (tj == 0) { pm[i] = m; ps[i] = s; }
    }
}

__global__ __launch_bounds__(256, 3) void k_neg(const float* __restrict__ E,
                                                const unsigned short* __restrict__ Hn,
                                                const int* __restrict__ tgt,
                                                const int* __restrict__ topi,
                                                const float* __restrict__ inv_full,
                                                const float* __restrict__ inv_low,
                                                float* __restrict__ pm_f, float* __restrict__ ps_f,
                                                float* __restrict__ pm_l, float* __restrict__ ps_l) {
    const int c  = blockIdx.x >> 3;
    const int jb = blockIdx.x & 7;
    const int tid  = threadIdx.x;
    const int w    = tid >> 6;    // wave id: cand-cols [w*64, w*64+64)
    const int lane = tid & 63;

    // union: staging tiles (e: 256x40 bf16 @0; h: 32x40 bf16 @20480) vs logits (32x260 f32)
    __shared__ __align__(16) char smem[33280];
    unsigned short* e_lds = (unsigned short*)smem;
    unsigned short* h_lds = (unsigned short*)(smem + 20480);
    float*          lgts  = (float*)smem;
    __shared__ int   cand_s[256];
    __shared__ float invf_s[256];
    __shared__ float invl_s[256];
    __shared__ int   tgt_s[32];

    if (tid < 32) tgt_s[tid] = tgt[c * 32 + tid];
    const int cd = topi[(size_t)c * K_CAND + jb * 256 + tid];
    cand_s[tid] = cd;
    invf_s[tid] = inv_full[cd];
    invl_s[tid] = inv_low[cd];

    const float* erow = E + (size_t)cd * D_DIM;
    const unsigned short* hsrc = Hn + (size_t)(c * 32 + (tid >> 2)) * D_DIM;

    f32x4 accF[2][4], accL[2][4];
#pragma unroll
    for (int r = 0; r < 2; ++r)
#pragma unroll
        for (int n = 0; n < 4; ++n) {
            accF[r][n] = f32x4{0.f, 0.f, 0.f, 0.f};
            accL[r][n] = f32x4{0.f, 0.f, 0.f, 0.f};
        }

    const int frow = lane & 15;
    const int kg   = lane >> 4;

#pragma unroll 1
    for (int kt = 0; kt < 32; ++kt) {
        __syncthreads();
        {
            const float4* ep = (const float4*)(erow + kt * 32);
            unsigned short* ew = &e_lds[tid * 40];
#pragma unroll
            for (int q = 0; q < 4; ++q) {
                const float4 fa = ep[2*q], fb = ep[2*q+1];
                uint4 u;
                u.x = pk_bf16(fa.x, fa.y);
                u.y = pk_bf16(fa.z, fa.w);
                u.z = pk_bf16(fb.x, fb.y);
                u.w = pk_bf16(fb.z, fb.w);
                *(uint4*)&ew[q * 8] = u;
            }
        }
        if (tid < 128) {
            const int hq = tid & 3;
            const uint4 hv = *(const uint4*)(hsrc + kt * 32 + hq * 8);
            *(uint4*)&h_lds[(tid >> 2) * 40 + hq * 8] = hv;
        }
        __syncthreads();
        const bf16x8 a0 = *(const bf16x8*)&h_lds[frow * 40 + kg * 8];
        const bf16x8 a1 = *(const bf16x8*)&h_lds[(frow + 16) * 40 + kg * 8];
#pragma unroll
        for (int n = 0; n < 4; ++n) {
            const bf16x8 b = *(const bf16x8*)&e_lds[(w * 64 + n * 16 + frow) * 40 + kg * 8];
            accF[0][n] = __builtin_amdgcn_mfma_f32_16x16x32_bf16(a0, b, accF[0][n], 0, 0, 0);
            accF[1][n] = __builtin_amdgcn_mfma_f32_16x16x32_bf16(a1, b, accF[1][n], 0, 0, 0);
            if (kt < 2) {
                accL[0][n] = __builtin_amdgcn_mfma_f32_16x16x32_bf16(a0, b, accL[0][n], 0, 0, 0);
                accL[1][n] = __builtin_amdgcn_mfma_f32_16x16x32_bf16(a1, b, accL[1][n], 0, 0, 0);
            }
        }
    }

    __syncthreads();
#pragma unroll
    for (int r = 0; r < 2; ++r)
#pragma unroll
        for (int n = 0; n < 4; ++n)
#pragma unroll
            for (int q = 0; q < 4; ++q) {
                const int i = r * 16 + kg * 4 + q;
                const int j = w * 64 + n * 16 + frow;
                float lg = SCALE_F * accF[r][n][q] * invf_s[j];
                if (cand_s[j] == tgt_s[i]) lg = NEG_BIG;
                lgts[i * 260 + j] = lg;
            }
    __syncthreads();
    row_reduce_store(lgts, w, lane, pm_f + ((size_t)c * 8 + jb) * 32, ps_f + ((size_t)c * 8 + jb) * 32);
    __syncthreads();
#pragma unroll
    for (int r = 0; r < 2; ++r)
#pragma unroll
        for (int n = 0; n < 4; ++n)
#pragma unroll
            for (int q = 0; q < 4; ++q) {
                const int i = r * 16 + kg * 4 + q;
                const int j = w * 64 + n * 16 + frow;
                float lg = SCALE_F * accL[r][n][q] * invl_s[j];
                if (cand_s[j] == tgt_s[i]) lg = NEG_BIG;
                lgts[i * 260 + j] = lg;
            }
    __syncthreads();
    row_reduce_store(lgts, w, lane, pm_l + ((size_t)c * 8 + jb) * 32, ps_l + ((size_t)c * 8 + jb) * 32);
}

// ---------------- K7: combine partials -> per-chunk loss ----------------
__global__ void k_loss(const float* __restrict__ pm_f, const float* __restrict__ ps_f,
                       const float* __restrict__ pm_l, const float* __restrict__ ps_l,
                       const float* __restrict__ pos_f, const float* __restrict__ pos_l,
                       float* __restrict__ closs) {
    const int c = blockIdx.x;
    const int tid = threadIdx.x;   // 64
    float val = 0.f;
    if (tid < 32) {
        const int i = tid;
        float lm, la;
        {
            float M = NEG_BIG;
            for (int jb = 0; jb < 8; ++jb) M = fmaxf(M, pm_f[((size_t)c * 8 + jb) * 32 + i]);
            float S = 0.f;
            for (int jb = 0; jb < 8; ++jb)
                S += ps_f[((size_t)c * 8 + jb) * 32 + i] * __expf(pm_f[((size_t)c * 8 + jb) * 32 + i] - M);
            const float p = SCALE_F * pos_f[c * 32 + i];
            const float M2 = fmaxf(M, p);
            const float S2 = __expf(p - M2) + S * __expf(M - M2);
            lm = (M2 + __logf(S2)) - p;
        }
        {
            float M = NEG_BIG;
            for (int jb = 0; jb < 8; ++jb) M = fmaxf(M, pm_l[((size_t)c * 8 + jb) * 32 + i]);
            float S = 0.f;
            for (int jb = 0; jb < 8; ++jb)
                S += ps_l[((size_t)c * 8 + jb) * 32 + i] * __expf(pm_l[((size_t)c * 8 + jb) * 32 + i] - M);
            const float p = SCALE_F * pos_l[c * 32 + i];
            const float M2 = fmaxf(M, p);
            const float S2 = __expf(p - M2) + S * __expf(M - M2);
            la = (M2 + __logf(S2)) - p;
        }
        val = lm + AUX_F * la;
    }
#pragma unroll
    for (int off = 32; off; off >>= 1) val += __shfl_xor(val, off);
    if (tid == 0) closs[c] = val;
}

// ---------------- K8: final scalar ----------------
__global__ void k_final(const float* __restrict__ closs, float* __restrict__ out) {
    const int tid = threadIdx.x;   // 64
    float v = closs[tid] + closs[tid + 64];
#pragma unroll
    for (int off = 32; off; off >>= 1) v += __shfl_xor(v, off);
    if (tid == 0) out[0] = v * (1.f / (float)N_ROWS);
}

extern "C" void kernel_launch(void* const* d_in, const int* in_sizes, int n_in,
                              void* d_out, int out_size, void* d_ws, size_t ws_size,
                              hipStream_t stream) {
    const float* H   = (const float*)d_in[0];
    const float* E   = (const float*)d_in[1];
    const int*   tgt = (const int*)d_in[2];
    float* out = (float*)d_out;
    float* w = (float*)d_ws;

    float* inv_full = w + OFF_INVF;
    float* inv_low  = w + OFF_INVL;
    float* h_inv    = w + OFF_HINV;
    float* h_mean   = w + OFF_HMEAN;
    float* pos_f    = w + OFF_POSF;
    float* pos_l    = w + OFF_POSL;
    float* closs    = w + OFF_CLOSS;
    float* pm_f     = w + OFF_PMF;
    float* ps_f     = w + OFF_PSF;
    float* pm_l     = w + OFF_PML;
    float* ps_l     = w + OFF_PSL;
    float* scan     = w + OFF_SCAN;
    int*   topi     = (int*)(w + OFF_TOPI);
    unsigned short* Hnbf = (unsigned short*)(w + OFF_HNBF);
    unsigned* gh1 = (unsigned*)(w + OFF_GH1);
    unsigned* gh2 = (unsigned*)(w + OFF_GH2);
    unsigned* gh3 = (unsigned*)(w + OFF_GH3);
    int* eql = (int*)(w + OFF_EQL);
    int* cnt = (int*)(w + OFF_CNT);

    k_vnorm <<<(V_SIZE + 3) / 4, 256, 0, stream>>>(E, inv_full, inv_low);
    k_hstats<<<N_CHUNKS, 256, 0, stream>>>(H, h_inv, h_mean, Hnbf);
    k_scan  <<<(V_SIZE + 255) / 256, 256, 0, stream>>>(E, h_mean, inv_low, scan, gh1, cnt);
    k_tkhist<<<N_CHUNKS * 8, 256, 0, stream>>>(scan, gh1);
    k_tksel2<<<N_CHUNKS * 8, 256, 0, stream>>>(scan, gh1, gh2);
    k_tksel3<<<N_CHUNKS * 8, 256, 0, stream>>>(scan, gh1, gh2, gh3);
    k_tkcmp <<<N_CHUNKS * 8, 256, 0, stream>>>(scan, gh1, gh2, gh3, topi, eql, cnt);
    k_tktie <<<N_CHUNKS, 64, 0, stream>>>(eql, cnt, topi);
    k_pos   <<<N_ROWS, 256, 0, stream>>>(H, E, tgt, h_inv, inv_full, inv_low, pos_f, pos_l);
    k_neg   <<<N_CHUNKS * 8, 256, 0, stream>>>(E, Hnbf, tgt, topi, inv_full, inv_low,
                                               pm_f, ps_f, pm_l, ps_l);
    k_loss  <<<N_CHUNKS, 64, 0, stream>>>(pm_f, ps_f, pm_l, ps_l, pos_f, pos_l, closs);
    k_final <<<1, 64, 0, stream>>>(closs, out);
}